// Round 6
// baseline (206.516 us; speedup 1.0000x reference)
//
#include <hip/hip_runtime.h>

// YOLOv1 loss, S=14, B=2, C=20, 30 fp32 channels/cell, 802816 cells.
// Persistent-wave pipelined version:
//   256 blocks x 256 thr (1 block/CU, LDS-forced). Each wave owns a
//   DOUBLE-BUFFERED async staging area (2 x [pred 7680B + tgt 7680B]) and
//   grid-strides over 12544 wave-tiles. Per iteration it issues the 18
//   global_load_lds for tile t+1024 into the other buffer, then waits
//   vmcnt(18) (current tile done, NEXT tile stays in flight) -> the memory
//   pipe never drains. Prior rounds all stalled at ~2.75 TB/s with a full
//   vmcnt(0) drain per tile.
// Stage 2: one block reduces 256 partials -> out.

typedef __attribute__((address_space(3))) void*       as3_void;
typedef const __attribute__((address_space(1))) void* as1_cvoid;

static __device__ __forceinline__ void gl_lds16(const float* g, float* l) {
    __builtin_amdgcn_global_load_lds((as1_cvoid)g, (as3_void)l, 16, 0, 0);
}
static __device__ __forceinline__ void gl_lds4(const float* g, float* l) {
    __builtin_amdgcn_global_load_lds((as1_cvoid)g, (as3_void)l, 4, 0, 0);
}

#define NTILES 12544           // 802816 cells / 64
#define WSTRIDE 1024           // 256 blocks x 4 waves

// s_waitcnt imm: [3:0]=vm[3:0], [6:4]=exp, [11:8]=lgkm, [15:14]=vm[5:4]
#define WAITCNT_VM18 (2 | (7<<4) | (15<<8) | (1<<14))   // vmcnt<=18, ignore exp/lgkm
#define WAITCNT_VM0  (0 | (7<<4) | (15<<8))             // vmcnt==0,  ignore exp/lgkm

__global__ __launch_bounds__(256) void yolo_loss_kernel(
    const float* __restrict__ pred, const float* __restrict__ target,
    float* __restrict__ partials)
{
    // [wave][phase][0..1919]=pred tile, [1920..3839]=target tile
    __shared__ float stage[4][2][3840];   // 122880 B -> 1 block/CU

    const int lane = threadIdx.x & 63;
    const int wid  = threadIdx.x >> 6;
    const int wgid = blockIdx.x * 4 + wid;          // 0..1023

    // ---- async stage of one tile (18 loads, no VGPR round-trip)
    auto stage_tile = [&](int t, float* dst) {
        const float* gp = pred   + (size_t)t * 1920;
        const float* gt = target + (size_t)t * 1920;
        float* dp = dst;
        float* dt = dst + 1920;
        #pragma unroll
        for (int i = 0; i < 7; ++i) gl_lds16(gp + i*256 + lane*4, dp + i*256);
        gl_lds4(gp + 1792 + lane, dp + 1792);
        gl_lds4(gp + 1856 + lane, dp + 1856);
        #pragma unroll
        for (int i = 0; i < 7; ++i) gl_lds16(gt + i*256 + lane*4, dt + i*256);
        gl_lds4(gt + 1792 + lane, dt + 1792);
        gl_lds4(gt + 1856 + lane, dt + 1856);
    };

    float acc = 0.0f;
    int ph = 0;
    int t = wgid;
    stage_tile(t, stage[wid][0]);

    while (t < NTILES) {
        const int nxt = t + WSTRIDE;
        const bool pre = (nxt < NTILES);            // wave-uniform
        if (pre) {
            stage_tile(nxt, stage[wid][ph ^ 1]);
            __builtin_amdgcn_s_waitcnt(WAITCNT_VM18);   // tile t ready; t+1024 in flight
        } else {
            __builtin_amdgcn_s_waitcnt(WAITCNT_VM0);
        }

        const float* swp = stage[wid][ph];
        const float* swt = swp + 1920;

        // ---- pred: LDS -> own cell's 30 floats
        float pv[30];
        {
            const float2* rp = (const float2*)&swp[lane * 30];
            #pragma unroll
            for (int j = 0; j < 15; ++j) {
                float2 a = rp[j]; pv[2*j] = a.x; pv[2*j+1] = a.y;
            }
        }
        // ---- target: 25 needed floats (ch 5..9 duplicate ch 0..4)
        float t0, t1, t2v, t3, t4;
        float tcls[20];
        {
            const float* tb = &swt[lane * 30];
            float2 a = *(const float2*)(tb + 0);
            float2 b = *(const float2*)(tb + 2);
            t0 = a.x; t1 = a.y; t2v = b.x; t3 = b.y;
            t4 = tb[4];
            const float2* tc = (const float2*)(tb + 10);
            #pragma unroll
            for (int j = 0; j < 10; ++j) {
                float2 c = tc[j]; tcls[2*j] = c.x; tcls[2*j+1] = c.y;
            }
        }

        // ---- per-cell loss (same math as verified rounds)
        const float invS = 1.0f / 14.0f;
        const bool obj = t4 > 0.0f;

        float tcx = t0 * invS, tcy = t1 * invS;
        float thw = 0.5f * t2v, thh = 0.5f * t3;
        float tx1 = tcx - thw, ty1 = tcy - thh;
        float tx2 = tcx + thw, ty2 = tcy + thh;
        float area_t = (tx2 - tx1) * (ty2 - ty1);

        float iou0 = 0.0f, iou1 = 0.0f;
        #pragma unroll
        for (int b = 0; b < 2; ++b) {
            float cx = pv[5*b + 0] * invS, cy = pv[5*b + 1] * invS;
            float hw = 0.5f * pv[5*b + 2], hh = 0.5f * pv[5*b + 3];
            float x1 = cx - hw, y1 = cy - hh, x2 = cx + hw, y2 = cy + hh;
            float lx = fmaxf(x1, tx1), ly = fmaxf(y1, ty1);
            float rx = fminf(x2, tx2), ry = fminf(y2, ty2);
            float w = fmaxf(rx - lx, 0.0f), h = fmaxf(ry - ly, 0.0f);
            float inter = w * h;
            float area_p = (x2 - x1) * (y2 - y1);
            float iou = inter / (area_p + area_t - inter);
            if (b == 0) iou0 = iou; else iou1 = iou;
        }
        const bool  sel     = iou1 > iou0;          // jnp.argmax: first max wins
        const float max_iou = fmaxf(iou0, iou1);

        float local;
        if (obj) {
            float pbx = sel ? pv[5] : pv[0];
            float pby = sel ? pv[6] : pv[1];
            float pbw = sel ? pv[7] : pv[2];
            float pbh = sel ? pv[8] : pv[3];
            float pbc = sel ? pv[9] : pv[4];

            float dx = pbx - t0, dy = pby - t1;
            float loss_xy = dx*dx + dy*dy;

            float sws = sqrtf(pbw) - sqrtf(t2v);
            float shs = sqrtf(pbh) - sqrtf(t3);
            float loss_wh = sws*sws + shs*shs;

            float dob = pbc - max_iou;
            float loss_obj = dob * dob;

            float loss_cls = 0.0f;
            #pragma unroll
            for (int c = 0; c < 20; ++c) {
                float d = pv[10 + c] - tcls[c];
                loss_cls = fmaf(d, d, loss_cls);
            }
            local = 5.0f * (loss_xy + loss_wh) + loss_obj + loss_cls;
        } else {
            float d0 = pv[4] - t4;
            float d1 = pv[9] - t4;
            local = 0.5f * (d0*d0 + d1*d1);
        }
        acc += local;

        ph ^= 1;
        t = nxt;
    }

    // ---- wave-64 shuffle reduction -> block partial -> one plain store
    #pragma unroll
    for (int off = 32; off > 0; off >>= 1)
        acc += __shfl_down(acc, off, 64);

    __shared__ float wsum[4];
    if (lane == 0) wsum[wid] = acc;
    __syncthreads();
    if (threadIdx.x == 0)
        partials[blockIdx.x] = wsum[0] + wsum[1] + wsum[2] + wsum[3];
}

__global__ __launch_bounds__(256) void reduce_kernel(
    const float* __restrict__ partials, float* __restrict__ out, int n)
{
    float local = 0.0f;
    for (int i = threadIdx.x; i < n; i += 256)
        local += partials[i];

    #pragma unroll
    for (int off = 32; off > 0; off >>= 1)
        local += __shfl_down(local, off, 64);

    __shared__ float wsum[4];
    const int lane = threadIdx.x & 63;
    const int wid  = threadIdx.x >> 6;
    if (lane == 0) wsum[wid] = local;
    __syncthreads();
    if (threadIdx.x == 0)
        out[0] = (wsum[0] + wsum[1] + wsum[2] + wsum[3]) * (1.0f / 4096.0f);
}

extern "C" void kernel_launch(void* const* d_in, const int* in_sizes, int n_in,
                              void* d_out, int out_size, void* d_ws, size_t ws_size,
                              hipStream_t stream) {
    const float* pred   = (const float*)d_in[0];
    const float* target = (const float*)d_in[1];
    float* out      = (float*)d_out;
    float* partials = (float*)d_ws;   // 256 floats

    yolo_loss_kernel<<<256, 256, 0, stream>>>(pred, target, partials);
    reduce_kernel<<<1, 256, 0, stream>>>(partials, out, 256);
}